// Round 11
// baseline (259.318 us; speedup 1.0000x reference)
//
#include <hip/hip_runtime.h>
#include <hip/hip_bf16.h>

#define D 128

typedef __attribute__((ext_vector_type(8))) short short8v;  // 8 bf16 (4 VGPRs)
typedef __attribute__((ext_vector_type(4))) float f32x4;

__device__ __forceinline__ short f2bf(float f) {
    union { float f; unsigned u; } v;
    v.f = f;
    unsigned u = v.u;
    unsigned r = (u + 0x7FFFu + ((u >> 16) & 1u)) >> 16;  // RNE
    return (short)r;
}

__device__ __forceinline__ float bf2f(unsigned u16) {
    union { unsigned u; float f; } v;
    v.u = u16 << 16;
    return v.f;
}

__device__ __forceinline__ unsigned pkbf2(float lo, float hi) {
    __hip_bfloat162 h = __float22bfloat162_rn(make_float2(lo, hi));
    union { __hip_bfloat162 h; unsigned u; } v;
    v.h = h;
    return v.u;
}

// ---------------- build: {hist | pack xb | pack WT2} -> scan -> fill, one kernel ------
// Grid = 1024 blocks, __launch_bounds__(256,4) caps VGPR so 4 blocks/CU are
// GUARANTEED co-resident (1024 <= 4*256) -> spin barriers are deadlock-free.
// Cross-block data re-read within the kernel goes through ATOMICS only (G16):
// counts (hist atomicAdd -> atomic load), bsums (atomicExch -> atomic load),
// cursor (atomicExch -> atomicAdd). rowptr/csr/xb/WT2 are plain (read by later
// kernels only; kernel boundary flushes).
__global__ __launch_bounds__(256, 4) void build_kernel(
    const int* __restrict__ src, const int* __restrict__ dst, int nE,
    const float* __restrict__ Ws, const float* __restrict__ Wn,
    short* __restrict__ WT2,
    const float* __restrict__ x, unsigned short* __restrict__ xb, int nElem,
    int* __restrict__ counts, int* __restrict__ bsums, int* __restrict__ barCnt,
    int* __restrict__ rowptr, int* __restrict__ csr, int n, int nb) {
    const int b = blockIdx.x, t = threadIdx.x, G = gridDim.x;
    const int gtid = b * 256 + t, gsz = G * 256;

    // P1a: degree histogram
    for (int e = gtid; e < nE; e += gsz) atomicAdd(&counts[dst[e]], 1);
    // P1b: pack xb = bf16(x)
    for (int i8 = gtid; i8 < nElem / 8; i8 += gsz) {
        const int base = i8 * 8;
        float4 lo = *reinterpret_cast<const float4*>(x + base);
        float4 hi = *reinterpret_cast<const float4*>(x + base + 4);
        union { short8v s8; unsigned u[4]; } p;
        p.u[0] = pkbf2(lo.x, lo.y);
        p.u[1] = pkbf2(lo.z, lo.w);
        p.u[2] = pkbf2(hi.x, hi.y);
        p.u[3] = pkbf2(hi.z, hi.w);
        *reinterpret_cast<short8v*>(xb + base) = p.s8;
    }
    // P1c: pack WT2[nn][k]: k<128 -> Ws[k][nn], else Wn[k-128][nn]
    for (int idx = gtid; idx < 256 * D; idx += gsz) {
        const int nn = idx >> 8, k = idx & 255;
        WT2[idx] = f2bf((k < D) ? Ws[k * D + nn] : Wn[(k - D) * D + nn]);
    }
    // ---- spin barrier 1 ----
    __syncthreads();
    if (t == 0) {
        atomicAdd(barCnt, 1);
        while (atomicAdd(barCnt, 0) < G) __builtin_amdgcn_s_sleep(2);
    }
    __syncthreads();

    // P2: per-chunk scan (blocks b < nb own 1024-element chunks)
    __shared__ int sh[256];
    __shared__ int red[8];
    const int i0 = b * 1024 + t * 4;
    int c0 = 0, c1 = 0, c2 = 0, c3 = 0, s = 0;
    if (b < nb) {
        c0 = (i0 + 0 < n) ? atomicAdd(&counts[i0 + 0], 0) : 0;
        c1 = (i0 + 1 < n) ? atomicAdd(&counts[i0 + 1], 0) : 0;
        c2 = (i0 + 2 < n) ? atomicAdd(&counts[i0 + 2], 0) : 0;
        c3 = (i0 + 3 < n) ? atomicAdd(&counts[i0 + 3], 0) : 0;
        s = c0 + c1 + c2 + c3;
        sh[t] = s;
        __syncthreads();
        for (int off = 1; off < 256; off <<= 1) {
            int u = (t >= off) ? sh[t - off] : 0;
            __syncthreads();
            sh[t] += u;
            __syncthreads();
        }
        if (t == 0) atomicExch(&bsums[b], sh[255]);
    }
    // ---- spin barrier 2 ----
    __syncthreads();
    if (t == 0) {
        atomicAdd(barCnt, 1);
        while (atomicAdd(barCnt, 0) < 2 * G) __builtin_amdgcn_s_sleep(2);
    }
    __syncthreads();

    if (b < nb) {
        int xv = (t < nb) ? atomicAdd(&bsums[t], 0) : 0;  // atomic load
        int vb = (t < b) ? xv : 0;
#pragma unroll
        for (int off = 32; off > 0; off >>= 1) {
            vb += __shfl_down(vb, off, 64);
            xv += __shfl_down(xv, off, 64);
        }
        if ((t & 63) == 0) { red[t >> 6] = vb; red[4 + (t >> 6)] = xv; }
        __syncthreads();
        const int base = red[0] + red[1] + red[2] + red[3];
        const int total = red[4] + red[5] + red[6] + red[7];
        int run = base + sh[t] - s;  // exclusive prefix for this thread's 4 elems
        if (i0 + 0 < n) { rowptr[i0 + 0] = run; atomicExch(&counts[i0 + 0], run); run += c0; }
        if (i0 + 1 < n) { rowptr[i0 + 1] = run; atomicExch(&counts[i0 + 1], run); run += c1; }
        if (i0 + 2 < n) { rowptr[i0 + 2] = run; atomicExch(&counts[i0 + 2], run); run += c2; }
        if (i0 + 3 < n) { rowptr[i0 + 3] = run; atomicExch(&counts[i0 + 3], run); run += c3; }
        if (b == 0 && t == 0) rowptr[n] = total;
    }
    // ---- spin barrier 3 ----
    __syncthreads();
    if (t == 0) {
        atomicAdd(barCnt, 1);
        while (atomicAdd(barCnt, 0) < 3 * G) __builtin_amdgcn_s_sleep(2);
    }
    __syncthreads();

    // P3: CSR fill
    for (int e = gtid; e < nE; e += gsz) {
        int pos = atomicAdd(&counts[dst[e]], 1);
        csr[pos] = src[e];
    }
}

// ---------------- gather: agg[d] = bf16(mean of xb[src] over csr[d]) ------------------
// 2 nodes/wave x 4-edge unroll = 8 row-loads in flight. lane = 2 channels (4B/row).
__global__ __launch_bounds__(256) void gather_kernel(const int* __restrict__ rowptr,
                                                     const int* __restrict__ csr,
                                                     const unsigned short* __restrict__ xb,
                                                     unsigned* __restrict__ aggOut,
                                                     int aggStride, int n) {
    const int wave = threadIdx.x >> 6;
    const int lane = threadIdx.x & 63;
    const int d0 = blockIdx.x * 8 + wave * 2;
    if (d0 >= n) return;  // no barriers
    const bool has1 = (d0 + 1) < n;

    const int begA = rowptr[d0];
    const int endA = rowptr[d0 + 1];
    const int begB = has1 ? endA : 0;
    const int endB = has1 ? rowptr[d0 + 2] : 0;
    const int ofs = lane * 2;
    float ax0 = 0.f, ay0 = 0.f, ax1 = 0.f, ay1 = 0.f;
    int iA = begA, iB = begB;

#define GLD(sidx) (*reinterpret_cast<const unsigned*>(xb + (size_t)(sidx) * D + ofs))
    while (iA + 4 <= endA && iB + 4 <= endB) {
        int a0 = csr[iA], a1 = csr[iA + 1], a2 = csr[iA + 2], a3 = csr[iA + 3];
        int b0 = csr[iB], b1 = csr[iB + 1], b2 = csr[iB + 2], b3 = csr[iB + 3];
        unsigned va0 = GLD(a0), va1 = GLD(a1), va2 = GLD(a2), va3 = GLD(a3);
        unsigned vb0 = GLD(b0), vb1 = GLD(b1), vb2 = GLD(b2), vb3 = GLD(b3);
        ax0 += (bf2f(va0 & 0xffffu) + bf2f(va1 & 0xffffu)) +
               (bf2f(va2 & 0xffffu) + bf2f(va3 & 0xffffu));
        ay0 += (bf2f(va0 >> 16) + bf2f(va1 >> 16)) + (bf2f(va2 >> 16) + bf2f(va3 >> 16));
        ax1 += (bf2f(vb0 & 0xffffu) + bf2f(vb1 & 0xffffu)) +
               (bf2f(vb2 & 0xffffu) + bf2f(vb3 & 0xffffu));
        ay1 += (bf2f(vb0 >> 16) + bf2f(vb1 >> 16)) + (bf2f(vb2 >> 16) + bf2f(vb3 >> 16));
        iA += 4;
        iB += 4;
    }
    while (iA + 4 <= endA) {
        int a0 = csr[iA], a1 = csr[iA + 1], a2 = csr[iA + 2], a3 = csr[iA + 3];
        unsigned va0 = GLD(a0), va1 = GLD(a1), va2 = GLD(a2), va3 = GLD(a3);
        ax0 += (bf2f(va0 & 0xffffu) + bf2f(va1 & 0xffffu)) +
               (bf2f(va2 & 0xffffu) + bf2f(va3 & 0xffffu));
        ay0 += (bf2f(va0 >> 16) + bf2f(va1 >> 16)) + (bf2f(va2 >> 16) + bf2f(va3 >> 16));
        iA += 4;
    }
    while (iB + 4 <= endB) {
        int b0 = csr[iB], b1 = csr[iB + 1], b2 = csr[iB + 2], b3 = csr[iB + 3];
        unsigned vb0 = GLD(b0), vb1 = GLD(b1), vb2 = GLD(b2), vb3 = GLD(b3);
        ax1 += (bf2f(vb0 & 0xffffu) + bf2f(vb1 & 0xffffu)) +
               (bf2f(vb2 & 0xffffu) + bf2f(vb3 & 0xffffu));
        ay1 += (bf2f(vb0 >> 16) + bf2f(vb1 >> 16)) + (bf2f(vb2 >> 16) + bf2f(vb3 >> 16));
        iB += 4;
    }
    while (iA < endA) {
        unsigned v = GLD(csr[iA]);
        ax0 += bf2f(v & 0xffffu);
        ay0 += bf2f(v >> 16);
        ++iA;
    }
    while (iB < endB) {
        unsigned v = GLD(csr[iB]);
        ax1 += bf2f(v & 0xffffu);
        ay1 += bf2f(v >> 16);
        ++iB;
    }
#undef GLD

    const float invA = 1.0f / fmaxf((float)(endA - begA), 1.0f);
    aggOut[(size_t)d0 * aggStride + lane] = pkbf2(ax0 * invA, ay0 * invA);
    if (has1) {
        const float invB = 1.0f / fmaxf((float)(endB - begB), 1.0f);
        aggOut[(size_t)(d0 + 1) * aggStride + lane] = pkbf2(ax1 * invB, ay1 * invB);
    }
}

// ---------------- GEMM K=256: out = relu([xb | agg] @ WT2^T + bs + bn) ----------------
// Swapped operands (mfma(W,x)): lane holds 4 consecutive channels of one row -> float4
// stores. Persistent, register double-buffer A-prefetch across grid-stride strips.
// INPLACE=true: agg lives in out rows -> barrier before stores orders RAW within block.
// INPLACE=false: agg in separate buffer -> NO barrier, pipeline never drains.
template <bool INPLACE>
__global__ __launch_bounds__(256) void gemm_kernel(const unsigned short* __restrict__ xb,
                                                   const short* __restrict__ WT2,
                                                   const float* __restrict__ bs,
                                                   const float* __restrict__ bn,
                                                   const unsigned* aggIn, int aggStride,
                                                   float* __restrict__ out, int nStrips) {
    const int wave = threadIdx.x >> 6;
    const int lane = threadIdx.x & 63;
    const int lrow = lane & 15;
    const int q = lane >> 4;
    const int ko = q * 8;

    short8v b[2][8];
#pragma unroll
    for (int j = 0; j < 2; ++j) {
        const short* __restrict__ wp = WT2 + (size_t)((wave * 2 + j) * 16 + lrow) * 256 + ko;
#pragma unroll
        for (int ks = 0; ks < 8; ++ks)
            b[j][ks] = *reinterpret_cast<const short8v*>(wp + ks * 32);
    }
    float4 bias[2];
#pragma unroll
    for (int j = 0; j < 2; ++j) {
        const int cb = (wave * 2 + j) * 16 + q * 4;
        float4 v1 = *reinterpret_cast<const float4*>(bs + cb);
        float4 v2 = *reinterpret_cast<const float4*>(bn + cb);
        bias[j] = make_float4(v1.x + v2.x, v1.y + v2.y, v1.z + v2.z, v1.w + v2.w);
    }

    const int stride = gridDim.x;

    auto loadA = [&](int strip, short8v* ax, uint4* ag) {
        const unsigned short* __restrict__ xr = xb + (size_t)(strip * 16 + lrow) * D + ko;
        const unsigned* __restrict__ ar = aggIn + (size_t)(strip * 16 + lrow) * aggStride;
#pragma unroll
        for (int ks = 0; ks < 4; ++ks) {
            ax[ks] = *reinterpret_cast<const short8v*>(xr + ks * 32);
            ag[ks] = *reinterpret_cast<const uint4*>(ar + q * 4 + ks * 16);
        }
    };

    auto compute = [&](int strip, const short8v* ax, const uint4* ag) {
        f32x4 acc[2];
        acc[0] = (f32x4){0.f, 0.f, 0.f, 0.f};
        acc[1] = (f32x4){0.f, 0.f, 0.f, 0.f};
#pragma unroll
        for (int j = 0; j < 2; ++j) {
#pragma unroll
            for (int ks = 0; ks < 4; ++ks) {
                union { uint4 u4; short8v s8; } cv;
                cv.u4 = ag[ks];
                acc[j] = __builtin_amdgcn_mfma_f32_16x16x32_bf16(b[j][ks], ax[ks], acc[j], 0, 0, 0);
                acc[j] = __builtin_amdgcn_mfma_f32_16x16x32_bf16(b[j][ks + 4], cv.s8, acc[j], 0, 0, 0);
            }
        }
        if (INPLACE) __syncthreads();  // all waves' agg (in out) consumed before stores
        const size_t rb = (size_t)(strip * 16 + lrow) * D;
#pragma unroll
        for (int j = 0; j < 2; ++j) {
            const int cb = (wave * 2 + j) * 16 + q * 4;
            float4 o;
            o.x = fmaxf(acc[j][0] + bias[j].x, 0.f);
            o.y = fmaxf(acc[j][1] + bias[j].y, 0.f);
            o.z = fmaxf(acc[j][2] + bias[j].z, 0.f);
            o.w = fmaxf(acc[j][3] + bias[j].w, 0.f);
            *reinterpret_cast<float4*>(out + rb + cb) = o;
        }
    };

    short8v axA[4], axB[4];
    uint4 agA[4], agB[4];
    int strip = blockIdx.x;
    if (strip >= nStrips) return;
    loadA(strip, axA, agA);
    for (; strip < nStrips; strip += 2 * stride) {
        const int s1 = strip + stride;
        if (s1 < nStrips) loadA(s1, axB, agB);
        compute(strip, axA, agA);
        if (s1 < nStrips) {
            const int s2 = s1 + stride;
            if (s2 < nStrips) loadA(s2, axA, agA);
            compute(s1, axB, agB);
        }
    }
}

extern "C" void kernel_launch(void* const* d_in, const int* in_sizes, int n_in,
                              void* d_out, int out_size, void* d_ws, size_t ws_size,
                              hipStream_t stream) {
    const float* x  = (const float*)d_in[0];
    const int*   ei = (const int*)d_in[1];
    const float* Ws = (const float*)d_in[2];
    const float* bs = (const float*)d_in[3];
    const float* Wn = (const float*)d_in[4];
    const float* bn = (const float*)d_in[5];
    float* out = (float*)d_out;

    const int n  = in_sizes[0] / D;   // 100000
    const int nE = in_sizes[1] / 2;   // 640000
    const int* src = ei;
    const int* dst = ei + nE;
    const int nb = (n + 1023) / 1024; // 98
    const int nElem = n * D;

    // workspace layout: base 29.0 MB (proven); + optional 25.6 MB aggb if ws allows
    char* w = (char*)d_ws;
    unsigned short* xb = (unsigned short*)w;  w += (size_t)nElem * 2;        // 25.6 MB
    short* WT2   = (short*)w;                 w += (size_t)256 * D * 2;      // 64 KB
    int* counts  = (int*)w;                   w += (size_t)n * 4;            // 0.4 MB
    int* bsums   = (int*)w;                   w += 1024 * 4;
    int* barCnt  = (int*)w;                   w += 16;
    int* rowptr  = (int*)w;                   w += (size_t)(n + 1) * 4;      // 0.4 MB
    int* csr     = (int*)w;                   w += (size_t)nE * 4;           // 2.56 MB
    size_t off = (size_t)(w - (char*)d_ws);
    off = (off + 15) & ~(size_t)15;
    unsigned short* aggb = (unsigned short*)((char*)d_ws + off);
    const bool sep = (off + (size_t)nElem * 2) <= ws_size;  // fixed per harness -> deterministic

    // zero counts + bsums + barCnt (contiguous)
    hipMemsetAsync(counts, 0, (size_t)(n + 1024 + 4) * sizeof(int), stream);

    build_kernel<<<1024, 256, 0, stream>>>(src, dst, nE, Ws, Wn, WT2, x, xb, nElem,
                                           counts, bsums, barCnt, rowptr, csr, n, nb);

    unsigned* aggPtr = sep ? (unsigned*)aggb : (unsigned*)out;
    const int aggStride = sep ? (D / 2) : D;  // dwords per row
    gather_kernel<<<(n + 7) / 8, 256, 0, stream>>>(rowptr, csr, xb, aggPtr, aggStride, n);

    const int nStrips = (n + 15) / 16;  // 6250 (n % 16 == 0)
    if (sep)
        gemm_kernel<false><<<2048, 256, 0, stream>>>(xb, WT2, bs, bn, (const unsigned*)aggb,
                                                     aggStride, out, nStrips);
    else
        gemm_kernel<true><<<2048, 256, 0, stream>>>(xb, WT2, bs, bn, (const unsigned*)out,
                                                    aggStride, out, nStrips);
}

// Round 12
// 163.168 us; speedup vs baseline: 1.5893x; 1.5893x over previous
//
#include <hip/hip_runtime.h>
#include <hip/hip_bf16.h>

#define D 128

typedef __attribute__((ext_vector_type(8))) short short8v;  // 8 bf16 (4 VGPRs)
typedef __attribute__((ext_vector_type(4))) float f32x4;

__device__ __forceinline__ short f2bf(float f) {
    union { float f; unsigned u; } v;
    v.f = f;
    unsigned u = v.u;
    unsigned r = (u + 0x7FFFu + ((u >> 16) & 1u)) >> 16;  // RNE
    return (short)r;
}

__device__ __forceinline__ float bf2f(unsigned u16) {
    union { unsigned u; float f; } v;
    v.u = u16 << 16;
    return v.f;
}

__device__ __forceinline__ unsigned pkbf2(float lo, float hi) {
    __hip_bfloat162 h = __float22bfloat162_rn(make_float2(lo, hi));
    union { __hip_bfloat162 h; unsigned u; } v;
    v.h = h;
    return v.u;
}

// ---------------- prep: role-split — hist(dst) | pack WT2 | pack xb ----------------
__global__ __launch_bounds__(256) void prep_kernel(const int* __restrict__ dst,
                                                   int* __restrict__ counts, int nE,
                                                   const float* __restrict__ Ws,
                                                   const float* __restrict__ Wn,
                                                   short* __restrict__ WT2,
                                                   const float* __restrict__ x,
                                                   unsigned short* __restrict__ xb,
                                                   int nElem) {
    const int nbE = (nE + 255) >> 8;
    const int b = blockIdx.x;
    if (b < nbE) {
        int e = b * 256 + threadIdx.x;
        if (e < nE) atomicAdd(&counts[dst[e]], 1);
    } else if (b < nbE + 128) {
        int idx = (b - nbE) * 256 + threadIdx.x;  // < 128*256 = 32768
        int nn = idx >> 8;
        int k = idx & 255;
        float v = (k < D) ? Ws[k * D + nn] : Wn[(k - D) * D + nn];
        WT2[idx] = f2bf(v);
    } else {
        int idx = (b - nbE - 128) * 256 + threadIdx.x;
        int base = idx * 8;
        if (base < nElem) {
            float4 lo = *reinterpret_cast<const float4*>(x + base);
            float4 hi = *reinterpret_cast<const float4*>(x + base + 4);
            union { short8v s8; unsigned u[4]; } p;
            p.u[0] = pkbf2(lo.x, lo.y);
            p.u[1] = pkbf2(lo.z, lo.w);
            p.u[2] = pkbf2(hi.x, hi.y);
            p.u[3] = pkbf2(hi.z, hi.w);
            *reinterpret_cast<short8v*>(xb + base) = p.s8;
        }
    }
}

// ---------------- single-kernel scan: counts -> rowptr + cursor init ----------------
// nb (=98) blocks co-resident (<< 256 CUs) -> done-counter spin is deadlock-free AND
// low-contention (98 pollers only; R11 showed 1024 pollers = contention storm).
__global__ __launch_bounds__(256) void scan_fused_kernel(int* __restrict__ counts,
                                                         int* __restrict__ bsums,
                                                         int* __restrict__ done,
                                                         int* __restrict__ rowptr,
                                                         int n, int nb) {
    __shared__ int sh[256];
    __shared__ int red[8];
    const int b = blockIdx.x;
    const int t = threadIdx.x;
    const int i0 = b * 1024 + t * 4;
    int c[4];
    int s = 0;
#pragma unroll
    for (int j = 0; j < 4; ++j) {
        c[j] = (i0 + j < n) ? counts[i0 + j] : 0;
        s += c[j];
    }
    sh[t] = s;
    __syncthreads();
    for (int off = 1; off < 256; off <<= 1) {
        int u = (t >= off) ? sh[t - off] : 0;
        __syncthreads();
        sh[t] += u;
        __syncthreads();
    }
    if (t == 0) {
        bsums[b] = sh[255];
        __threadfence();
        atomicAdd(done, 1);
        while (atomicAdd(done, 0) < nb) { }
    }
    __syncthreads();
    int xv = (t < nb) ? atomicAdd(&bsums[t], 0) : 0;  // atomic load, cross-XCD safe
    int vb = (t < b) ? xv : 0;
#pragma unroll
    for (int off = 32; off > 0; off >>= 1) {
        vb += __shfl_down(vb, off, 64);
        xv += __shfl_down(xv, off, 64);
    }
    if ((t & 63) == 0) { red[t >> 6] = vb; red[4 + (t >> 6)] = xv; }
    __syncthreads();
    const int base = red[0] + red[1] + red[2] + red[3];
    const int total = red[4] + red[5] + red[6] + red[7];
    int run = base + sh[t] - s;
#pragma unroll
    for (int j = 0; j < 4; ++j) {
        int i = i0 + j;
        if (i < n) {
            rowptr[i] = run;
            counts[i] = run;  // cursor init
            run += c[j];
        }
    }
    if (b == nb - 1 && t == 0) rowptr[n] = total;
}

// ---------------- CSR fill: csr[pos] = src, pos = cursor[dst]++ ----------------
__global__ __launch_bounds__(256) void fill_kernel(const int* __restrict__ src,
                                                   const int* __restrict__ dst,
                                                   int* __restrict__ cursor,
                                                   int* __restrict__ csr, int nE) {
    int e = blockIdx.x * 256 + threadIdx.x;
    if (e < nE) {
        int pos = atomicAdd(&cursor[dst[e]], 1);
        csr[pos] = src[e];
    }
}

// ---------------- gather: agg[d] = bf16(mean of xb[src] over csr[d]) ------------------
// 2 nodes/wave x 4-edge unroll = 8 row-loads in flight. lane = 2 channels (4B/row).
__global__ __launch_bounds__(256) void gather_kernel(const int* __restrict__ rowptr,
                                                     const int* __restrict__ csr,
                                                     const unsigned short* __restrict__ xb,
                                                     unsigned* __restrict__ aggOut,
                                                     int aggStride, int n) {
    const int wave = threadIdx.x >> 6;
    const int lane = threadIdx.x & 63;
    const int d0 = blockIdx.x * 8 + wave * 2;
    if (d0 >= n) return;  // no barriers
    const bool has1 = (d0 + 1) < n;

    const int begA = rowptr[d0];
    const int endA = rowptr[d0 + 1];
    const int begB = has1 ? endA : 0;
    const int endB = has1 ? rowptr[d0 + 2] : 0;
    const int ofs = lane * 2;
    float ax0 = 0.f, ay0 = 0.f, ax1 = 0.f, ay1 = 0.f;
    int iA = begA, iB = begB;

#define GLD(sidx) (*reinterpret_cast<const unsigned*>(xb + (size_t)(sidx) * D + ofs))
    while (iA + 4 <= endA && iB + 4 <= endB) {
        int a0 = csr[iA], a1 = csr[iA + 1], a2 = csr[iA + 2], a3 = csr[iA + 3];
        int b0 = csr[iB], b1 = csr[iB + 1], b2 = csr[iB + 2], b3 = csr[iB + 3];
        unsigned va0 = GLD(a0), va1 = GLD(a1), va2 = GLD(a2), va3 = GLD(a3);
        unsigned vb0 = GLD(b0), vb1 = GLD(b1), vb2 = GLD(b2), vb3 = GLD(b3);
        ax0 += (bf2f(va0 & 0xffffu) + bf2f(va1 & 0xffffu)) +
               (bf2f(va2 & 0xffffu) + bf2f(va3 & 0xffffu));
        ay0 += (bf2f(va0 >> 16) + bf2f(va1 >> 16)) + (bf2f(va2 >> 16) + bf2f(va3 >> 16));
        ax1 += (bf2f(vb0 & 0xffffu) + bf2f(vb1 & 0xffffu)) +
               (bf2f(vb2 & 0xffffu) + bf2f(vb3 & 0xffffu));
        ay1 += (bf2f(vb0 >> 16) + bf2f(vb1 >> 16)) + (bf2f(vb2 >> 16) + bf2f(vb3 >> 16));
        iA += 4;
        iB += 4;
    }
    while (iA + 4 <= endA) {
        int a0 = csr[iA], a1 = csr[iA + 1], a2 = csr[iA + 2], a3 = csr[iA + 3];
        unsigned va0 = GLD(a0), va1 = GLD(a1), va2 = GLD(a2), va3 = GLD(a3);
        ax0 += (bf2f(va0 & 0xffffu) + bf2f(va1 & 0xffffu)) +
               (bf2f(va2 & 0xffffu) + bf2f(va3 & 0xffffu));
        ay0 += (bf2f(va0 >> 16) + bf2f(va1 >> 16)) + (bf2f(va2 >> 16) + bf2f(va3 >> 16));
        iA += 4;
    }
    while (iB + 4 <= endB) {
        int b0 = csr[iB], b1 = csr[iB + 1], b2 = csr[iB + 2], b3 = csr[iB + 3];
        unsigned vb0 = GLD(b0), vb1 = GLD(b1), vb2 = GLD(b2), vb3 = GLD(b3);
        ax1 += (bf2f(vb0 & 0xffffu) + bf2f(vb1 & 0xffffu)) +
               (bf2f(vb2 & 0xffffu) + bf2f(vb3 & 0xffffu));
        ay1 += (bf2f(vb0 >> 16) + bf2f(vb1 >> 16)) + (bf2f(vb2 >> 16) + bf2f(vb3 >> 16));
        iB += 4;
    }
    while (iA < endA) {
        unsigned v = GLD(csr[iA]);
        ax0 += bf2f(v & 0xffffu);
        ay0 += bf2f(v >> 16);
        ++iA;
    }
    while (iB < endB) {
        unsigned v = GLD(csr[iB]);
        ax1 += bf2f(v & 0xffffu);
        ay1 += bf2f(v >> 16);
        ++iB;
    }
#undef GLD

    const float invA = 1.0f / fmaxf((float)(endA - begA), 1.0f);
    aggOut[(size_t)d0 * aggStride + lane] = pkbf2(ax0 * invA, ay0 * invA);
    if (has1) {
        const float invB = 1.0f / fmaxf((float)(endB - begB), 1.0f);
        aggOut[(size_t)(d0 + 1) * aggStride + lane] = pkbf2(ax1 * invB, ay1 * invB);
    }
}

// ---------------- GEMM K=256: out = relu([xb | agg] @ WT2^T + bs + bn) ----------------
// Swapped operands (mfma(W,x)): lane holds 4 consecutive channels of one row -> float4
// stores. Persistent, register double-buffer A-prefetch across grid-stride strips.
// INPLACE=false: agg in separate buffer -> NO barrier, pipeline never drains.
template <bool INPLACE>
__global__ __launch_bounds__(256) void gemm_kernel(const unsigned short* __restrict__ xb,
                                                   const short* __restrict__ WT2,
                                                   const float* __restrict__ bs,
                                                   const float* __restrict__ bn,
                                                   const unsigned* aggIn, int aggStride,
                                                   float* __restrict__ out, int nStrips) {
    const int wave = threadIdx.x >> 6;
    const int lane = threadIdx.x & 63;
    const int lrow = lane & 15;
    const int q = lane >> 4;
    const int ko = q * 8;

    short8v b[2][8];
#pragma unroll
    for (int j = 0; j < 2; ++j) {
        const short* __restrict__ wp = WT2 + (size_t)((wave * 2 + j) * 16 + lrow) * 256 + ko;
#pragma unroll
        for (int ks = 0; ks < 8; ++ks)
            b[j][ks] = *reinterpret_cast<const short8v*>(wp + ks * 32);
    }
    float4 bias[2];
#pragma unroll
    for (int j = 0; j < 2; ++j) {
        const int cb = (wave * 2 + j) * 16 + q * 4;
        float4 v1 = *reinterpret_cast<const float4*>(bs + cb);
        float4 v2 = *reinterpret_cast<const float4*>(bn + cb);
        bias[j] = make_float4(v1.x + v2.x, v1.y + v2.y, v1.z + v2.z, v1.w + v2.w);
    }

    const int stride = gridDim.x;

    auto loadA = [&](int strip, short8v* ax, uint4* ag) {
        const unsigned short* __restrict__ xr = xb + (size_t)(strip * 16 + lrow) * D + ko;
        const unsigned* __restrict__ ar = aggIn + (size_t)(strip * 16 + lrow) * aggStride;
#pragma unroll
        for (int ks = 0; ks < 4; ++ks) {
            ax[ks] = *reinterpret_cast<const short8v*>(xr + ks * 32);
            ag[ks] = *reinterpret_cast<const uint4*>(ar + q * 4 + ks * 16);
        }
    };

    auto compute = [&](int strip, const short8v* ax, const uint4* ag) {
        f32x4 acc[2];
        acc[0] = (f32x4){0.f, 0.f, 0.f, 0.f};
        acc[1] = (f32x4){0.f, 0.f, 0.f, 0.f};
#pragma unroll
        for (int j = 0; j < 2; ++j) {
#pragma unroll
            for (int ks = 0; ks < 4; ++ks) {
                union { uint4 u4; short8v s8; } cv;
                cv.u4 = ag[ks];
                acc[j] = __builtin_amdgcn_mfma_f32_16x16x32_bf16(b[j][ks], ax[ks], acc[j], 0, 0, 0);
                acc[j] = __builtin_amdgcn_mfma_f32_16x16x32_bf16(b[j][ks + 4], cv.s8, acc[j], 0, 0, 0);
            }
        }
        if (INPLACE) __syncthreads();  // all waves' agg (in out) consumed before stores
        const size_t rb = (size_t)(strip * 16 + lrow) * D;
#pragma unroll
        for (int j = 0; j < 2; ++j) {
            const int cb = (wave * 2 + j) * 16 + q * 4;
            float4 o;
            o.x = fmaxf(acc[j][0] + bias[j].x, 0.f);
            o.y = fmaxf(acc[j][1] + bias[j].y, 0.f);
            o.z = fmaxf(acc[j][2] + bias[j].z, 0.f);
            o.w = fmaxf(acc[j][3] + bias[j].w, 0.f);
            *reinterpret_cast<float4*>(out + rb + cb) = o;
        }
    };

    short8v axA[4], axB[4];
    uint4 agA[4], agB[4];
    int strip = blockIdx.x;
    if (strip >= nStrips) return;
    loadA(strip, axA, agA);
    for (; strip < nStrips; strip += 2 * stride) {
        const int s1 = strip + stride;
        if (s1 < nStrips) loadA(s1, axB, agB);
        compute(strip, axA, agA);
        if (s1 < nStrips) {
            const int s2 = s1 + stride;
            if (s2 < nStrips) loadA(s2, axA, agA);
            compute(s1, axB, agB);
        }
    }
}

extern "C" void kernel_launch(void* const* d_in, const int* in_sizes, int n_in,
                              void* d_out, int out_size, void* d_ws, size_t ws_size,
                              hipStream_t stream) {
    const float* x  = (const float*)d_in[0];
    const int*   ei = (const int*)d_in[1];
    const float* Ws = (const float*)d_in[2];
    const float* bs = (const float*)d_in[3];
    const float* Wn = (const float*)d_in[4];
    const float* bn = (const float*)d_in[5];
    float* out = (float*)d_out;

    const int n  = in_sizes[0] / D;   // 100000
    const int nE = in_sizes[1] / 2;   // 640000
    const int* src = ei;
    const int* dst = ei + nE;
    const int nb = (n + 1023) / 1024; // 98 (<=128, co-resident)
    const int nElem = n * D;

    // workspace layout: base ~29.1 MB (proven); + optional 25.6 MB aggb if ws allows
    char* w = (char*)d_ws;
    unsigned short* xb = (unsigned short*)w;  w += (size_t)nElem * 2;        // 25.6 MB
    short* WT2   = (short*)w;                 w += (size_t)256 * D * 2;      // 64 KB
    int* counts  = (int*)w;                   w += (size_t)n * 4;            // 0.4 MB
    int* bsums   = (int*)w;                   w += 128 * 4;
    int* done    = (int*)w;                   w += 16;
    int* rowptr  = (int*)w;                   w += (size_t)(n + 1) * 4;      // 0.4 MB
    int* csr     = (int*)w;                   w += (size_t)nE * 4;           // 2.56 MB
    size_t off = (size_t)(w - (char*)d_ws);
    off = (off + 15) & ~(size_t)15;
    unsigned short* aggb = (unsigned short*)((char*)d_ws + off);
    const bool sep = (off + (size_t)nElem * 2) <= ws_size;  // fixed per harness -> deterministic

    const int nbE = (nE + 255) / 256;              // 2500
    const int nXb = (nElem / 8 + 255) / 256;       // 6250

    // zero counts + bsums + done (contiguous)
    hipMemsetAsync(counts, 0, (size_t)(n + 128 + 4) * sizeof(int), stream);
    prep_kernel<<<nbE + 128 + nXb, 256, 0, stream>>>(dst, counts, nE, Ws, Wn, WT2, x, xb, nElem);
    scan_fused_kernel<<<nb, 256, 0, stream>>>(counts, bsums, done, rowptr, n, nb);
    fill_kernel<<<(nE + 255) / 256, 256, 0, stream>>>(src, dst, counts, csr, nE);

    unsigned* aggPtr = sep ? (unsigned*)aggb : (unsigned*)out;
    const int aggStride = sep ? (D / 2) : D;  // dwords per row
    gather_kernel<<<(n + 7) / 8, 256, 0, stream>>>(rowptr, csr, xb, aggPtr, aggStride, n);

    const int nStrips = (n + 15) / 16;  // 6250 (n % 16 == 0)
    if (sep)
        gemm_kernel<false><<<2048, 256, 0, stream>>>(xb, WT2, bs, bn, (const unsigned*)aggb,
                                                     aggStride, out, nStrips);
    else
        gemm_kernel<true><<<2048, 256, 0, stream>>>(xb, WT2, bs, bn, (const unsigned*)out,
                                                    aggStride, out, nStrips);
}

// Round 14
// 158.120 us; speedup vs baseline: 1.6400x; 1.0319x over previous
//
#include <hip/hip_runtime.h>
#include <hip/hip_bf16.h>

#define D 128

typedef __attribute__((ext_vector_type(8))) short short8v;  // 8 bf16 (4 VGPRs)
typedef __attribute__((ext_vector_type(4))) float f32x4;

__device__ __forceinline__ short f2bf(float f) {
    union { float f; unsigned u; } v;
    v.f = f;
    unsigned u = v.u;
    unsigned r = (u + 0x7FFFu + ((u >> 16) & 1u)) >> 16;  // RNE
    return (short)r;
}

__device__ __forceinline__ float bf2f(unsigned u16) {
    union { unsigned u; float f; } v;
    v.u = u16 << 16;
    return v.f;
}

__device__ __forceinline__ unsigned pkbf2(float lo, float hi) {
    __hip_bfloat162 h = __float22bfloat162_rn(make_float2(lo, hi));
    union { __hip_bfloat162 h; unsigned u; } v;
    v.h = h;
    return v.u;
}

// ---------------- prep: role-split — hist(dst) | pack WT2 | pack xb ----------------
__global__ __launch_bounds__(256) void prep_kernel(const int* __restrict__ dst,
                                                   int* __restrict__ counts, int nE,
                                                   const float* __restrict__ Ws,
                                                   const float* __restrict__ Wn,
                                                   short* __restrict__ WT2,
                                                   const float* __restrict__ x,
                                                   unsigned short* __restrict__ xb,
                                                   int nElem) {
    const int nbE = (nE + 255) >> 8;
    const int b = blockIdx.x;
    if (b < nbE) {
        int e = b * 256 + threadIdx.x;
        if (e < nE) atomicAdd(&counts[dst[e]], 1);
    } else if (b < nbE + 128) {
        int idx = (b - nbE) * 256 + threadIdx.x;  // < 128*256 = 32768
        int nn = idx >> 8;
        int k = idx & 255;
        float v = (k < D) ? Ws[k * D + nn] : Wn[(k - D) * D + nn];
        WT2[idx] = f2bf(v);
    } else {
        int idx = (b - nbE - 128) * 256 + threadIdx.x;
        int base = idx * 8;
        if (base < nElem) {
            float4 lo = *reinterpret_cast<const float4*>(x + base);
            float4 hi = *reinterpret_cast<const float4*>(x + base + 4);
            union { short8v s8; unsigned u[4]; } p;
            p.u[0] = pkbf2(lo.x, lo.y);
            p.u[1] = pkbf2(lo.z, lo.w);
            p.u[2] = pkbf2(hi.x, hi.y);
            p.u[3] = pkbf2(hi.z, hi.w);
            *reinterpret_cast<short8v*>(xb + base) = p.s8;
        }
    }
}

// ---------------- scan + CSR fill, one kernel ----------------
// nb (=98) blocks co-resident -> done-counter spin is deadlock-free and
// low-contention (98 pollers; R11: 1024 pollers = contention storm).
// Cross-block cursor handoff via atomics only (G16).
__global__ __launch_bounds__(256) void scan_fill_kernel(int* __restrict__ counts,
                                                        int* __restrict__ bsums,
                                                        int* __restrict__ done,
                                                        int* __restrict__ rowptr,
                                                        const int* __restrict__ src,
                                                        const int* __restrict__ dst,
                                                        int* __restrict__ csr, int nE,
                                                        int n, int nb) {
    __shared__ int sh[256];
    __shared__ int red[8];
    const int b = blockIdx.x;
    const int t = threadIdx.x;
    const int i0 = b * 1024 + t * 4;
    int c[4];
    int s = 0;
#pragma unroll
    for (int j = 0; j < 4; ++j) {
        c[j] = (i0 + j < n) ? counts[i0 + j] : 0;
        s += c[j];
    }
    sh[t] = s;
    __syncthreads();
    for (int off = 1; off < 256; off <<= 1) {
        int u = (t >= off) ? sh[t - off] : 0;
        __syncthreads();
        sh[t] += u;
        __syncthreads();
    }
    if (t == 0) {
        bsums[b] = sh[255];
        __threadfence();
        atomicAdd(done, 1);
        while (atomicAdd(done, 0) < nb) { }
    }
    __syncthreads();
    int xv = (t < nb) ? atomicAdd(&bsums[t], 0) : 0;  // atomic load, cross-XCD safe
    int vb = (t < b) ? xv : 0;
#pragma unroll
    for (int off = 32; off > 0; off >>= 1) {
        vb += __shfl_down(vb, off, 64);
        xv += __shfl_down(xv, off, 64);
    }
    if ((t & 63) == 0) { red[t >> 6] = vb; red[4 + (t >> 6)] = xv; }
    __syncthreads();
    const int base = red[0] + red[1] + red[2] + red[3];
    const int total = red[4] + red[5] + red[6] + red[7];
    int run = base + sh[t] - s;
#pragma unroll
    for (int j = 0; j < 4; ++j) {
        int i = i0 + j;
        if (i < n) {
            rowptr[i] = run;
            atomicExch(&counts[i], run);  // cursor init, device-scope visible
            run += c[j];
        }
    }
    if (b == nb - 1 && t == 0) rowptr[n] = total;

    // ---- spin barrier 2: all cursors initialized ----
    __syncthreads();
    if (t == 0) {
        atomicAdd(done, 1);
        while (atomicAdd(done, 0) < 2 * nb) { }
    }
    __syncthreads();

    // ---- CSR fill (grid-stride, 98*256 = 25088 threads, ~26 edges each) ----
    const int gsz = nb * 256;
    for (int e = b * 256 + t; e < nE; e += gsz) {
        int pos = atomicAdd(&counts[dst[e]], 1);
        csr[pos] = src[e];
    }
}

// ---------------- gather: agg[d] = bf16(mean of xb[src] over csr[d]) ------------------
// 2 nodes/wave x 4-edge unroll = 8 row-loads in flight. lane = 2 channels (4B/row).
__global__ __launch_bounds__(256) void gather_kernel(const int* __restrict__ rowptr,
                                                     const int* __restrict__ csr,
                                                     const unsigned short* __restrict__ xb,
                                                     unsigned* __restrict__ aggOut,
                                                     int aggStride, int n) {
    const int wave = threadIdx.x >> 6;
    const int lane = threadIdx.x & 63;
    const int d0 = blockIdx.x * 8 + wave * 2;
    if (d0 >= n) return;  // no barriers
    const bool has1 = (d0 + 1) < n;

    const int begA = rowptr[d0];
    const int endA = rowptr[d0 + 1];
    const int begB = has1 ? endA : 0;
    const int endB = has1 ? rowptr[d0 + 2] : 0;
    const int ofs = lane * 2;
    float ax0 = 0.f, ay0 = 0.f, ax1 = 0.f, ay1 = 0.f;
    int iA = begA, iB = begB;

#define GLD(sidx) (*reinterpret_cast<const unsigned*>(xb + (size_t)(sidx) * D + ofs))
    while (iA + 4 <= endA && iB + 4 <= endB) {
        int a0 = csr[iA], a1 = csr[iA + 1], a2 = csr[iA + 2], a3 = csr[iA + 3];
        int b0 = csr[iB], b1 = csr[iB + 1], b2 = csr[iB + 2], b3 = csr[iB + 3];
        unsigned va0 = GLD(a0), va1 = GLD(a1), va2 = GLD(a2), va3 = GLD(a3);
        unsigned vb0 = GLD(b0), vb1 = GLD(b1), vb2 = GLD(b2), vb3 = GLD(b3);
        ax0 += (bf2f(va0 & 0xffffu) + bf2f(va1 & 0xffffu)) +
               (bf2f(va2 & 0xffffu) + bf2f(va3 & 0xffffu));
        ay0 += (bf2f(va0 >> 16) + bf2f(va1 >> 16)) + (bf2f(va2 >> 16) + bf2f(va3 >> 16));
        ax1 += (bf2f(vb0 & 0xffffu) + bf2f(vb1 & 0xffffu)) +
               (bf2f(vb2 & 0xffffu) + bf2f(vb3 & 0xffffu));
        ay1 += (bf2f(vb0 >> 16) + bf2f(vb1 >> 16)) + (bf2f(vb2 >> 16) + bf2f(vb3 >> 16));
        iA += 4;
        iB += 4;
    }
    while (iA + 4 <= endA) {
        int a0 = csr[iA], a1 = csr[iA + 1], a2 = csr[iA + 2], a3 = csr[iA + 3];
        unsigned va0 = GLD(a0), va1 = GLD(a1), va2 = GLD(a2), va3 = GLD(a3);
        ax0 += (bf2f(va0 & 0xffffu) + bf2f(va1 & 0xffffu)) +
               (bf2f(va2 & 0xffffu) + bf2f(va3 & 0xffffu));
        ay0 += (bf2f(va0 >> 16) + bf2f(va1 >> 16)) + (bf2f(va2 >> 16) + bf2f(va3 >> 16));
        iA += 4;
    }
    while (iB + 4 <= endB) {
        int b0 = csr[iB], b1 = csr[iB + 1], b2 = csr[iB + 2], b3 = csr[iB + 3];
        unsigned vb0 = GLD(b0), vb1 = GLD(b1), vb2 = GLD(b2), vb3 = GLD(b3);
        ax1 += (bf2f(vb0 & 0xffffu) + bf2f(vb1 & 0xffffu)) +
               (bf2f(vb2 & 0xffffu) + bf2f(vb3 & 0xffffu));
        ay1 += (bf2f(vb0 >> 16) + bf2f(vb1 >> 16)) + (bf2f(vb2 >> 16) + bf2f(vb3 >> 16));
        iB += 4;
    }
    while (iA < endA) {
        unsigned v = GLD(csr[iA]);
        ax0 += bf2f(v & 0xffffu);
        ay0 += bf2f(v >> 16);
        ++iA;
    }
    while (iB < endB) {
        unsigned v = GLD(csr[iB]);
        ax1 += bf2f(v & 0xffffu);
        ay1 += bf2f(v >> 16);
        ++iB;
    }
#undef GLD

    const float invA = 1.0f / fmaxf((float)(endA - begA), 1.0f);
    aggOut[(size_t)d0 * aggStride + lane] = pkbf2(ax0 * invA, ay0 * invA);
    if (has1) {
        const float invB = 1.0f / fmaxf((float)(endB - begB), 1.0f);
        aggOut[(size_t)(d0 + 1) * aggStride + lane] = pkbf2(ax1 * invB, ay1 * invB);
    }
}

// ---------------- GEMM K=256: out = relu([xb | agg] @ WT2^T + bs + bn) ----------------
// Swapped operands (mfma(W,x)): lane holds 4 consecutive channels of one row.
// NONTEMPORAL f32x4 stores (out is write-once, never re-read) to bypass L2
// write-allocate on the 64B-granule store pattern. Grid 1024 = single residency
// round (~4 blocks/CU), ~6 strips/block, register double-buffered A prefetch.
template <bool INPLACE>
__global__ __launch_bounds__(256) void gemm_kernel(const unsigned short* __restrict__ xb,
                                                   const short* __restrict__ WT2,
                                                   const float* __restrict__ bs,
                                                   const float* __restrict__ bn,
                                                   const unsigned* aggIn, int aggStride,
                                                   float* __restrict__ out, int nStrips) {
    const int wave = threadIdx.x >> 6;
    const int lane = threadIdx.x & 63;
    const int lrow = lane & 15;
    const int q = lane >> 4;
    const int ko = q * 8;

    short8v b[2][8];
#pragma unroll
    for (int j = 0; j < 2; ++j) {
        const short* __restrict__ wp = WT2 + (size_t)((wave * 2 + j) * 16 + lrow) * 256 + ko;
#pragma unroll
        for (int ks = 0; ks < 8; ++ks)
            b[j][ks] = *reinterpret_cast<const short8v*>(wp + ks * 32);
    }
    float4 bias[2];
#pragma unroll
    for (int j = 0; j < 2; ++j) {
        const int cb = (wave * 2 + j) * 16 + q * 4;
        float4 v1 = *reinterpret_cast<const float4*>(bs + cb);
        float4 v2 = *reinterpret_cast<const float4*>(bn + cb);
        bias[j] = make_float4(v1.x + v2.x, v1.y + v2.y, v1.z + v2.z, v1.w + v2.w);
    }

    const int stride = gridDim.x;

    auto loadA = [&](int strip, short8v* ax, uint4* ag) {
        const unsigned short* __restrict__ xr = xb + (size_t)(strip * 16 + lrow) * D + ko;
        const unsigned* __restrict__ ar = aggIn + (size_t)(strip * 16 + lrow) * aggStride;
#pragma unroll
        for (int ks = 0; ks < 4; ++ks) {
            ax[ks] = *reinterpret_cast<const short8v*>(xr + ks * 32);
            ag[ks] = *reinterpret_cast<const uint4*>(ar + q * 4 + ks * 16);
        }
    };

    auto compute = [&](int strip, const short8v* ax, const uint4* ag) {
        f32x4 acc[2];
        acc[0] = (f32x4){0.f, 0.f, 0.f, 0.f};
        acc[1] = (f32x4){0.f, 0.f, 0.f, 0.f};
#pragma unroll
        for (int j = 0; j < 2; ++j) {
#pragma unroll
            for (int ks = 0; ks < 4; ++ks) {
                union { uint4 u4; short8v s8; } cv;
                cv.u4 = ag[ks];
                acc[j] = __builtin_amdgcn_mfma_f32_16x16x32_bf16(b[j][ks], ax[ks], acc[j], 0, 0, 0);
                acc[j] = __builtin_amdgcn_mfma_f32_16x16x32_bf16(b[j][ks + 4], cv.s8, acc[j], 0, 0, 0);
            }
        }
        if (INPLACE) __syncthreads();  // all waves' agg (in out) consumed before stores
        const size_t rb = (size_t)(strip * 16 + lrow) * D;
#pragma unroll
        for (int j = 0; j < 2; ++j) {
            const int cb = (wave * 2 + j) * 16 + q * 4;
            f32x4 o;
            o[0] = fmaxf(acc[j][0] + bias[j].x, 0.f);
            o[1] = fmaxf(acc[j][1] + bias[j].y, 0.f);
            o[2] = fmaxf(acc[j][2] + bias[j].z, 0.f);
            o[3] = fmaxf(acc[j][3] + bias[j].w, 0.f);
            __builtin_nontemporal_store(o, reinterpret_cast<f32x4*>(out + rb + cb));
        }
    };

    short8v axA[4], axB[4];
    uint4 agA[4], agB[4];
    int strip = blockIdx.x;
    if (strip >= nStrips) return;
    loadA(strip, axA, agA);
    for (; strip < nStrips; strip += 2 * stride) {
        const int s1 = strip + stride;
        if (s1 < nStrips) loadA(s1, axB, agB);
        compute(strip, axA, agA);
        if (s1 < nStrips) {
            const int s2 = s1 + stride;
            if (s2 < nStrips) loadA(s2, axA, agA);
            compute(s1, axB, agB);
        }
    }
}

extern "C" void kernel_launch(void* const* d_in, const int* in_sizes, int n_in,
                              void* d_out, int out_size, void* d_ws, size_t ws_size,
                              hipStream_t stream) {
    const float* x  = (const float*)d_in[0];
    const int*   ei = (const int*)d_in[1];
    const float* Ws = (const float*)d_in[2];
    const float* bs = (const float*)d_in[3];
    const float* Wn = (const float*)d_in[4];
    const float* bn = (const float*)d_in[5];
    float* out = (float*)d_out;

    const int n  = in_sizes[0] / D;   // 100000
    const int nE = in_sizes[1] / 2;   // 640000
    const int* src = ei;
    const int* dst = ei + nE;
    const int nb = (n + 1023) / 1024; // 98 (<=128, co-resident)
    const int nElem = n * D;

    // workspace layout: base ~29.1 MB (proven); + optional 25.6 MB aggb if ws allows
    char* w = (char*)d_ws;
    unsigned short* xb = (unsigned short*)w;  w += (size_t)nElem * 2;        // 25.6 MB
    short* WT2   = (short*)w;                 w += (size_t)256 * D * 2;      // 64 KB
    int* counts  = (int*)w;                   w += (size_t)n * 4;            // 0.4 MB
    int* bsums   = (int*)w;                   w += 128 * 4;
    int* done    = (int*)w;                   w += 16;
    int* rowptr  = (int*)w;                   w += (size_t)(n + 1) * 4;      // 0.4 MB
    int* csr     = (int*)w;                   w += (size_t)nE * 4;           // 2.56 MB
    size_t off = (size_t)(w - (char*)d_ws);
    off = (off + 15) & ~(size_t)15;
    unsigned short* aggb = (unsigned short*)((char*)d_ws + off);
    const bool sep = (off + (size_t)nElem * 2) <= ws_size;  // fixed per harness -> deterministic

    const int nbE = (nE + 255) / 256;              // 2500
    const int nXb = (nElem / 8 + 255) / 256;       // 6250

    // zero counts + bsums + done (contiguous)
    (void)hipMemsetAsync(counts, 0, (size_t)(n + 128 + 4) * sizeof(int), stream);
    prep_kernel<<<nbE + 128 + nXb, 256, 0, stream>>>(dst, counts, nE, Ws, Wn, WT2, x, xb, nElem);
    scan_fill_kernel<<<nb, 256, 0, stream>>>(counts, bsums, done, rowptr, src, dst, csr, nE, n, nb);

    unsigned* aggPtr = sep ? (unsigned*)aggb : (unsigned*)out;
    const int aggStride = sep ? (D / 2) : D;  // dwords per row
    gather_kernel<<<(n + 7) / 8, 256, 0, stream>>>(rowptr, csr, xb, aggPtr, aggStride, n);

    const int nStrips = (n + 15) / 16;  // 6250 (n % 16 == 0)
    if (sep)
        gemm_kernel<false><<<1024, 256, 0, stream>>>(xb, WT2, bs, bn, (const unsigned*)aggb,
                                                     aggStride, out, nStrips);
    else
        gemm_kernel<true><<<1024, 256, 0, stream>>>(xb, WT2, bs, bn, (const unsigned*)out,
                                                    aggStride, out, nStrips);
}

// Round 15
// 154.357 us; speedup vs baseline: 1.6800x; 1.0244x over previous
//
#include <hip/hip_runtime.h>
#include <hip/hip_bf16.h>

#define D 128

typedef __attribute__((ext_vector_type(8))) short short8v;  // 8 bf16 (4 VGPRs)
typedef __attribute__((ext_vector_type(4))) float f32x4;

__device__ __forceinline__ short f2bf(float f) {
    union { float f; unsigned u; } v;
    v.f = f;
    unsigned u = v.u;
    unsigned r = (u + 0x7FFFu + ((u >> 16) & 1u)) >> 16;  // RNE
    return (short)r;
}

__device__ __forceinline__ float bf2f(unsigned u16) {
    union { unsigned u; float f; } v;
    v.u = u16 << 16;
    return v.f;
}

__device__ __forceinline__ unsigned pkbf2(float lo, float hi) {
    __hip_bfloat162 h = __float22bfloat162_rn(make_float2(lo, hi));
    union { __hip_bfloat162 h; unsigned u; } v;
    v.h = h;
    return v.u;
}

// ---------------- prep: role-split — hist(dst) | pack WT2 | pack xb ----------------
__global__ __launch_bounds__(256) void prep_kernel(const int* __restrict__ dst,
                                                   int* __restrict__ counts, int nE,
                                                   const float* __restrict__ Ws,
                                                   const float* __restrict__ Wn,
                                                   short* __restrict__ WT2,
                                                   const float* __restrict__ x,
                                                   unsigned short* __restrict__ xb,
                                                   int nElem) {
    const int nbE = (nE + 255) >> 8;
    const int b = blockIdx.x;
    if (b < nbE) {
        int e = b * 256 + threadIdx.x;
        if (e < nE) atomicAdd(&counts[dst[e]], 1);
    } else if (b < nbE + 128) {
        int idx = (b - nbE) * 256 + threadIdx.x;  // < 128*256 = 32768
        int nn = idx >> 8;
        int k = idx & 255;
        float v = (k < D) ? Ws[k * D + nn] : Wn[(k - D) * D + nn];
        WT2[idx] = f2bf(v);
    } else {
        int idx = (b - nbE - 128) * 256 + threadIdx.x;
        int base = idx * 8;
        if (base < nElem) {
            float4 lo = *reinterpret_cast<const float4*>(x + base);
            float4 hi = *reinterpret_cast<const float4*>(x + base + 4);
            union { short8v s8; unsigned u[4]; } p;
            p.u[0] = pkbf2(lo.x, lo.y);
            p.u[1] = pkbf2(lo.z, lo.w);
            p.u[2] = pkbf2(hi.x, hi.y);
            p.u[3] = pkbf2(hi.z, hi.w);
            *reinterpret_cast<short8v*>(xb + base) = p.s8;
        }
    }
}

// ---------------- single-kernel scan: counts -> rowptr + cursor init ----------------
// nb (=98) blocks co-resident -> done-counter spin is deadlock-free and
// low-contention (98 pollers; R11: 1024 pollers = contention storm).
__global__ __launch_bounds__(256) void scan_fused_kernel(int* __restrict__ counts,
                                                         int* __restrict__ bsums,
                                                         int* __restrict__ done,
                                                         int* __restrict__ rowptr,
                                                         int n, int nb) {
    __shared__ int sh[256];
    __shared__ int red[8];
    const int b = blockIdx.x;
    const int t = threadIdx.x;
    const int i0 = b * 1024 + t * 4;
    int c[4];
    int s = 0;
#pragma unroll
    for (int j = 0; j < 4; ++j) {
        c[j] = (i0 + j < n) ? counts[i0 + j] : 0;
        s += c[j];
    }
    sh[t] = s;
    __syncthreads();
    for (int off = 1; off < 256; off <<= 1) {
        int u = (t >= off) ? sh[t - off] : 0;
        __syncthreads();
        sh[t] += u;
        __syncthreads();
    }
    if (t == 0) {
        bsums[b] = sh[255];
        __threadfence();
        atomicAdd(done, 1);
        while (atomicAdd(done, 0) < nb) { }
    }
    __syncthreads();
    int xv = (t < nb) ? atomicAdd(&bsums[t], 0) : 0;  // atomic load, cross-XCD safe
    int vb = (t < b) ? xv : 0;
#pragma unroll
    for (int off = 32; off > 0; off >>= 1) {
        vb += __shfl_down(vb, off, 64);
        xv += __shfl_down(xv, off, 64);
    }
    if ((t & 63) == 0) { red[t >> 6] = vb; red[4 + (t >> 6)] = xv; }
    __syncthreads();
    const int base = red[0] + red[1] + red[2] + red[3];
    const int total = red[4] + red[5] + red[6] + red[7];
    int run = base + sh[t] - s;
#pragma unroll
    for (int j = 0; j < 4; ++j) {
        int i = i0 + j;
        if (i < n) {
            rowptr[i] = run;
            counts[i] = run;  // cursor init (read by later kernel -> boundary flush)
            run += c[j];
        }
    }
    if (b == nb - 1 && t == 0) rowptr[n] = total;
}

// ---------------- CSR fill: csr[pos] = src, pos = cursor[dst]++ (2500 blocks!) --------
// R14 lesson: folding this into the 98-block scan starved it (58us @ 3.6% occupancy);
// edge-parallel atomic chains need the wide grid (12us at 2500 blocks).
__global__ __launch_bounds__(256) void fill_kernel(const int* __restrict__ src,
                                                   const int* __restrict__ dst,
                                                   int* __restrict__ cursor,
                                                   int* __restrict__ csr, int nE) {
    int e = blockIdx.x * 256 + threadIdx.x;
    if (e < nE) {
        int pos = atomicAdd(&cursor[dst[e]], 1);
        csr[pos] = src[e];
    }
}

// ---------------- gather: agg[d] = bf16(mean of xb[src] over csr[d]) ------------------
// 2 nodes/wave x 4-edge unroll = 8 row-loads in flight. lane = 2 channels (4B/row).
__global__ __launch_bounds__(256) void gather_kernel(const int* __restrict__ rowptr,
                                                     const int* __restrict__ csr,
                                                     const unsigned short* __restrict__ xb,
                                                     unsigned* __restrict__ aggOut,
                                                     int aggStride, int n) {
    const int wave = threadIdx.x >> 6;
    const int lane = threadIdx.x & 63;
    const int d0 = blockIdx.x * 8 + wave * 2;
    if (d0 >= n) return;  // no barriers
    const bool has1 = (d0 + 1) < n;

    const int begA = rowptr[d0];
    const int endA = rowptr[d0 + 1];
    const int begB = has1 ? endA : 0;
    const int endB = has1 ? rowptr[d0 + 2] : 0;
    const int ofs = lane * 2;
    float ax0 = 0.f, ay0 = 0.f, ax1 = 0.f, ay1 = 0.f;
    int iA = begA, iB = begB;

#define GLD(sidx) (*reinterpret_cast<const unsigned*>(xb + (size_t)(sidx) * D + ofs))
    while (iA + 4 <= endA && iB + 4 <= endB) {
        int a0 = csr[iA], a1 = csr[iA + 1], a2 = csr[iA + 2], a3 = csr[iA + 3];
        int b0 = csr[iB], b1 = csr[iB + 1], b2 = csr[iB + 2], b3 = csr[iB + 3];
        unsigned va0 = GLD(a0), va1 = GLD(a1), va2 = GLD(a2), va3 = GLD(a3);
        unsigned vb0 = GLD(b0), vb1 = GLD(b1), vb2 = GLD(b2), vb3 = GLD(b3);
        ax0 += (bf2f(va0 & 0xffffu) + bf2f(va1 & 0xffffu)) +
               (bf2f(va2 & 0xffffu) + bf2f(va3 & 0xffffu));
        ay0 += (bf2f(va0 >> 16) + bf2f(va1 >> 16)) + (bf2f(va2 >> 16) + bf2f(va3 >> 16));
        ax1 += (bf2f(vb0 & 0xffffu) + bf2f(vb1 & 0xffffu)) +
               (bf2f(vb2 & 0xffffu) + bf2f(vb3 & 0xffffu));
        ay1 += (bf2f(vb0 >> 16) + bf2f(vb1 >> 16)) + (bf2f(vb2 >> 16) + bf2f(vb3 >> 16));
        iA += 4;
        iB += 4;
    }
    while (iA + 4 <= endA) {
        int a0 = csr[iA], a1 = csr[iA + 1], a2 = csr[iA + 2], a3 = csr[iA + 3];
        unsigned va0 = GLD(a0), va1 = GLD(a1), va2 = GLD(a2), va3 = GLD(a3);
        ax0 += (bf2f(va0 & 0xffffu) + bf2f(va1 & 0xffffu)) +
               (bf2f(va2 & 0xffffu) + bf2f(va3 & 0xffffu));
        ay0 += (bf2f(va0 >> 16) + bf2f(va1 >> 16)) + (bf2f(va2 >> 16) + bf2f(va3 >> 16));
        iA += 4;
    }
    while (iB + 4 <= endB) {
        int b0 = csr[iB], b1 = csr[iB + 1], b2 = csr[iB + 2], b3 = csr[iB + 3];
        unsigned vb0 = GLD(b0), vb1 = GLD(b1), vb2 = GLD(b2), vb3 = GLD(b3);
        ax1 += (bf2f(vb0 & 0xffffu) + bf2f(vb1 & 0xffffu)) +
               (bf2f(vb2 & 0xffffu) + bf2f(vb3 & 0xffffu));
        ay1 += (bf2f(vb0 >> 16) + bf2f(vb1 >> 16)) + (bf2f(vb2 >> 16) + bf2f(vb3 >> 16));
        iB += 4;
    }
    while (iA < endA) {
        unsigned v = GLD(csr[iA]);
        ax0 += bf2f(v & 0xffffu);
        ay0 += bf2f(v >> 16);
        ++iA;
    }
    while (iB < endB) {
        unsigned v = GLD(csr[iB]);
        ax1 += bf2f(v & 0xffffu);
        ay1 += bf2f(v >> 16);
        ++iB;
    }
#undef GLD

    const float invA = 1.0f / fmaxf((float)(endA - begA), 1.0f);
    aggOut[(size_t)d0 * aggStride + lane] = pkbf2(ax0 * invA, ay0 * invA);
    if (has1) {
        const float invB = 1.0f / fmaxf((float)(endB - begB), 1.0f);
        aggOut[(size_t)(d0 + 1) * aggStride + lane] = pkbf2(ax1 * invB, ay1 * invB);
    }
}

// ---------------- GEMM K=256: out = relu([xb | agg] @ WT2^T + bs + bn) ----------------
// Swapped operands (mfma(W,x)): lane holds 4 consecutive channels of one row.
// NONTEMPORAL f32x4 stores; grid 1024 = single residency round, register
// double-buffered A prefetch.
template <bool INPLACE>
__global__ __launch_bounds__(256) void gemm_kernel(const unsigned short* __restrict__ xb,
                                                   const short* __restrict__ WT2,
                                                   const float* __restrict__ bs,
                                                   const float* __restrict__ bn,
                                                   const unsigned* aggIn, int aggStride,
                                                   float* __restrict__ out, int nStrips) {
    const int wave = threadIdx.x >> 6;
    const int lane = threadIdx.x & 63;
    const int lrow = lane & 15;
    const int q = lane >> 4;
    const int ko = q * 8;

    short8v b[2][8];
#pragma unroll
    for (int j = 0; j < 2; ++j) {
        const short* __restrict__ wp = WT2 + (size_t)((wave * 2 + j) * 16 + lrow) * 256 + ko;
#pragma unroll
        for (int ks = 0; ks < 8; ++ks)
            b[j][ks] = *reinterpret_cast<const short8v*>(wp + ks * 32);
    }
    float4 bias[2];
#pragma unroll
    for (int j = 0; j < 2; ++j) {
        const int cb = (wave * 2 + j) * 16 + q * 4;
        float4 v1 = *reinterpret_cast<const float4*>(bs + cb);
        float4 v2 = *reinterpret_cast<const float4*>(bn + cb);
        bias[j] = make_float4(v1.x + v2.x, v1.y + v2.y, v1.z + v2.z, v1.w + v2.w);
    }

    const int stride = gridDim.x;

    auto loadA = [&](int strip, short8v* ax, uint4* ag) {
        const unsigned short* __restrict__ xr = xb + (size_t)(strip * 16 + lrow) * D + ko;
        const unsigned* __restrict__ ar = aggIn + (size_t)(strip * 16 + lrow) * aggStride;
#pragma unroll
        for (int ks = 0; ks < 4; ++ks) {
            ax[ks] = *reinterpret_cast<const short8v*>(xr + ks * 32);
            ag[ks] = *reinterpret_cast<const uint4*>(ar + q * 4 + ks * 16);
        }
    };

    auto compute = [&](int strip, const short8v* ax, const uint4* ag) {
        f32x4 acc[2];
        acc[0] = (f32x4){0.f, 0.f, 0.f, 0.f};
        acc[1] = (f32x4){0.f, 0.f, 0.f, 0.f};
#pragma unroll
        for (int j = 0; j < 2; ++j) {
#pragma unroll
            for (int ks = 0; ks < 4; ++ks) {
                union { uint4 u4; short8v s8; } cv;
                cv.u4 = ag[ks];
                acc[j] = __builtin_amdgcn_mfma_f32_16x16x32_bf16(b[j][ks], ax[ks], acc[j], 0, 0, 0);
                acc[j] = __builtin_amdgcn_mfma_f32_16x16x32_bf16(b[j][ks + 4], cv.s8, acc[j], 0, 0, 0);
            }
        }
        if (INPLACE) __syncthreads();  // all waves' agg (in out) consumed before stores
        const size_t rb = (size_t)(strip * 16 + lrow) * D;
#pragma unroll
        for (int j = 0; j < 2; ++j) {
            const int cb = (wave * 2 + j) * 16 + q * 4;
            f32x4 o;
            o[0] = fmaxf(acc[j][0] + bias[j].x, 0.f);
            o[1] = fmaxf(acc[j][1] + bias[j].y, 0.f);
            o[2] = fmaxf(acc[j][2] + bias[j].z, 0.f);
            o[3] = fmaxf(acc[j][3] + bias[j].w, 0.f);
            __builtin_nontemporal_store(o, reinterpret_cast<f32x4*>(out + rb + cb));
        }
    };

    short8v axA[4], axB[4];
    uint4 agA[4], agB[4];
    int strip = blockIdx.x;
    if (strip >= nStrips) return;
    loadA(strip, axA, agA);
    for (; strip < nStrips; strip += 2 * stride) {
        const int s1 = strip + stride;
        if (s1 < nStrips) loadA(s1, axB, agB);
        compute(strip, axA, agA);
        if (s1 < nStrips) {
            const int s2 = s1 + stride;
            if (s2 < nStrips) loadA(s2, axA, agA);
            compute(s1, axB, agB);
        }
    }
}

extern "C" void kernel_launch(void* const* d_in, const int* in_sizes, int n_in,
                              void* d_out, int out_size, void* d_ws, size_t ws_size,
                              hipStream_t stream) {
    const float* x  = (const float*)d_in[0];
    const int*   ei = (const int*)d_in[1];
    const float* Ws = (const float*)d_in[2];
    const float* bs = (const float*)d_in[3];
    const float* Wn = (const float*)d_in[4];
    const float* bn = (const float*)d_in[5];
    float* out = (float*)d_out;

    const int n  = in_sizes[0] / D;   // 100000
    const int nE = in_sizes[1] / 2;   // 640000
    const int* src = ei;
    const int* dst = ei + nE;
    const int nb = (n + 1023) / 1024; // 98 (<=128, co-resident)
    const int nElem = n * D;

    // workspace layout: base ~29.1 MB (proven); + optional 25.6 MB aggb if ws allows
    char* w = (char*)d_ws;
    unsigned short* xb = (unsigned short*)w;  w += (size_t)nElem * 2;        // 25.6 MB
    short* WT2   = (short*)w;                 w += (size_t)256 * D * 2;      // 64 KB
    int* counts  = (int*)w;                   w += (size_t)n * 4;            // 0.4 MB
    int* bsums   = (int*)w;                   w += 128 * 4;
    int* done    = (int*)w;                   w += 16;
    int* rowptr  = (int*)w;                   w += (size_t)(n + 1) * 4;      // 0.4 MB
    int* csr     = (int*)w;                   w += (size_t)nE * 4;           // 2.56 MB
    size_t off = (size_t)(w - (char*)d_ws);
    off = (off + 15) & ~(size_t)15;
    unsigned short* aggb = (unsigned short*)((char*)d_ws + off);
    const bool sep = (off + (size_t)nElem * 2) <= ws_size;  // fixed per harness -> deterministic

    const int nbE = (nE + 255) / 256;              // 2500
    const int nXb = (nElem / 8 + 255) / 256;       // 6250

    // zero counts + bsums + done (contiguous)
    (void)hipMemsetAsync(counts, 0, (size_t)(n + 128 + 4) * sizeof(int), stream);
    prep_kernel<<<nbE + 128 + nXb, 256, 0, stream>>>(dst, counts, nE, Ws, Wn, WT2, x, xb, nElem);
    scan_fused_kernel<<<nb, 256, 0, stream>>>(counts, bsums, done, rowptr, n, nb);
    fill_kernel<<<(nE + 255) / 256, 256, 0, stream>>>(src, dst, counts, csr, nE);

    unsigned* aggPtr = sep ? (unsigned*)aggb : (unsigned*)out;
    const int aggStride = sep ? (D / 2) : D;  // dwords per row
    gather_kernel<<<(n + 7) / 8, 256, 0, stream>>>(rowptr, csr, xb, aggPtr, aggStride, n);

    const int nStrips = (n + 15) / 16;  // 6250 (n % 16 == 0)
    if (sep)
        gemm_kernel<false><<<1024, 256, 0, stream>>>(xb, WT2, bs, bn, (const unsigned*)aggb,
                                                     aggStride, out, nStrips);
    else
        gemm_kernel<true><<<1024, 256, 0, stream>>>(xb, WT2, bs, bn, (const unsigned*)out,
                                                    aggStride, out, nStrips);
}